// Round 12
// baseline (318.691 us; speedup 1.0000x reference)
//
#include <hip/hip_runtime.h>
#include <math.h>

typedef __bf16 bf16;
typedef __bf16 bf16x8 __attribute__((ext_vector_type(8)));
typedef __bf16 bf16x4 __attribute__((ext_vector_type(4)));
typedef float  f32x4  __attribute__((ext_vector_type(4)));

#define HW        16384      // 128*128
#define OUT_ELEMS 4194304    // 4*64*128*128

// padded xm: [b][m][yp=142][xp=142][c=64], pixel (y,x) at (y+7, x+7)
#define XM_ROW    (142 * 64)
#define XM_PLANE  (142 * XM_ROW)          // 1,290,496 el
// padded cat: [b][yp=130][xp=130][ch=256], pixel (y,x) at (y+1, x+1)
#define CAT_ROW   (130 * 256)
#define CAT_PLANE (130 * CAT_ROW)         // 4,326,400 el

// LDS pixel stride (elements): 64 payload + 8 pad -> 144 B (16B-aligned rows,
// 2-way bank aliasing = free; smaller pads either break b128 alignment or
// create >=4-way conflicts)
#define LPX 72

// ------ weight transforms (fp32 -> bf16) + cat_p halo zero -------------------
// kern_t lane-major (r10 layout): kern_t[(bm*9+tap)*4096 + (mt*2+kci)*512 + lane*8 + j]
//   o = mt*16 + (lane&15), c = kci*32 + (lane>>4)*8 + j
// w2_t lane-major layout (same recipe):
//   w2_t[((tap*4 + cq)*8 + mt*2+kci)*512 + lane*8 + j]
//   oc = mt*16 + (lane&15), ch = cq*64 + kci*32 + (lane>>4)*8 + j
__global__ void k_wt(const float* __restrict__ kern, const float* __restrict__ w2,
                     bf16* __restrict__ kern_t, bf16* __restrict__ w2_t,
                     bf16* __restrict__ cat_p) {
  int blk = blockIdx.x;
  if (blk >= 2304) {                      // ---- halo zeroing ----
    int id = (blk - 2304) * 256 + threadIdx.x;
    if (id >= 4 * 16512) return;
    int plane = id / 16512, j = id % 16512;
    bf16* base = cat_p + (size_t)plane * CAT_PLANE;
    bf16x8 zv = {};
    if (j < 8320) {                       // rows 0 and 129, full 130 px
      int row = (j / 4160) * 129;
      int off = (j % 4160) * 8;
      *(bf16x8*)(base + (size_t)row * CAT_ROW + off) = zv;
    } else {                              // rows 1..128, cols 0 and 129
      int k = j - 8320;
      int row = 1 + (k >> 6);
      int idx = k & 63;
      int col = (idx >> 5) * 129;
      int ch8 = (idx & 31) * 8;
      *(bf16x8*)(base + (size_t)row * CAT_ROW + col * 256 + ch8) = zv;
    }
    return;
  }
  int i = blk * 256 + threadIdx.x;
  const int N1 = 4 * 3 * 9 * 64 * 64;   // 442368
  if (i < N1) {
    int j    = i & 7;
    int lane = (i >> 3) & 63;
    int km   = (i >> 9) & 7;            // kci = km&1, mt = km>>1
    int tap  = (i >> 12) % 9;
    int bm   = i / 36864;
    int o = (km >> 1) * 16 + (lane & 15);
    int c = (km & 1) * 32 + (lane >> 4) * 8 + j;
    kern_t[i] = (bf16)kern[(((bm * 64 + o) * 64 + c) * 9) + tap];
  } else {
    int j = i - N1;
    if (j < 64 * 256 * 9) {             // 147,456 el
      int j8   = j & 7;
      int lane = (j >> 3) & 63;
      int km   = (j >> 9) & 7;          // kci = km&1, mt = km>>1
      int cq   = (j >> 12) & 3;
      int tap  = j >> 14;               // 0..8
      int oc = (km >> 1) * 16 + (lane & 15);
      int ch = cq * 64 + (km & 1) * 32 + (lane >> 4) * 8 + j8;
      w2_t[j] = (bf16)w2[(oc * 256 + ch) * 9 + tap];
    }
  }
}

// -------- mask conv stage 1: partial logits over 8-channel groups ------------
__global__ void k_mask1(const float* __restrict__ x, const float* __restrict__ mw,
                        float* __restrict__ part) {
  int y = blockIdx.x, b = blockIdx.y, cg = blockIdx.z;
  int tx = threadIdx.x;      // 0..127
  float a0 = 0.f, a1 = 0.f, a2 = 0.f;
#pragma unroll
  for (int ci = 0; ci < 8; ++ci) {
    int c = cg * 8 + ci;
    const float* xp = x + ((size_t)(b * 64 + c)) * HW;
    const float* w0 = mw + (0 * 64 + c) * 9;
    const float* w1 = mw + (1 * 64 + c) * 9;
    const float* w2 = mw + (2 * 64 + c) * 9;
#pragma unroll
    for (int ky = 0; ky < 3; ++ky) {
      int yy = y + ky - 1;
      if ((unsigned)yy >= 128u) continue;
#pragma unroll
      for (int kx = 0; kx < 3; ++kx) {
        int xx = tx + kx - 1;
        if ((unsigned)xx >= 128u) continue;
        float xv = xp[yy * 128 + xx];
        a0 += xv * w0[ky * 3 + kx];
        a1 += xv * w1[ky * 3 + kx];
        a2 += xv * w2[ky * 3 + kx];
      }
    }
  }
  size_t base = (size_t)((b * 8 + cg) * 3) * HW + y * 128 + tx;
  part[base]          = a0;
  part[base + HW]     = a1;
  part[base + 2 * HW] = a2;
}

// -------- mask conv stage 2: reduce groups + bias + softmax ------------------
__global__ void k_mask2(const float* __restrict__ part, const float* __restrict__ mb,
                        float* __restrict__ masks) {
  int y = blockIdx.x, b = blockIdx.y;
  int tx = threadIdx.x;
  float a0 = mb[0], a1 = mb[1], a2 = mb[2];
  int off = y * 128 + tx;
#pragma unroll
  for (int cg = 0; cg < 8; ++cg) {
    size_t base = (size_t)((b * 8 + cg) * 3) * HW + off;
    a0 += part[base];
    a1 += part[base + HW];
    a2 += part[base + 2 * HW];
  }
  float mx = fmaxf(a0, fmaxf(a1, a2));
  float e0 = __expf(a0 - mx), e1 = __expf(a1 - mx), e2 = __expf(a2 - mx);
  float inv = 1.0f / (e0 + e1 + e2);
  size_t base = ((size_t)b * 3) * HW + off;
  masks[base]          = e0 * inv;
  masks[base + HW]     = e1 * inv;
  masks[base + 2 * HW] = e2 * inv;
}

// -------- xm = x * mask, NCHW fp32 -> padded NHWC(c=64) bf16, incl. halo -----
__global__ void k_xmt(const float* __restrict__ x, const float* __restrict__ masks,
                      bf16* __restrict__ xm_p) {
  int yp = blockIdx.x;  // 0..141 padded row
  int m = blockIdx.y, b = blockIdx.z;
  int t = threadIdx.x;  // 256
  bf16* prow = xm_p + (size_t)(b * 3 + m) * XM_PLANE + (size_t)yp * XM_ROW;
  bf16x8 z = {};
  if (yp < 7 || yp >= 135) {          // full halo row: 142*64/8 = 1136 chunks
#pragma unroll
    for (int i = 0; i < 5; ++i) {
      int u = i * 256 + t;
      if (u < 1136) ((bf16x8*)prow)[u] = z;
    }
    return;
  }
  // side halo: 7 px * 64c = 448 el = 56 chunks each side
  if (t < 56) ((bf16x8*)prow)[t] = z;
  else if (t < 112) ((bf16x8*)(prow + 135 * 64))[t - 56] = z;

  int y = yp - 7;
  __shared__ float tile[64 * 130];
#pragma unroll
  for (int i = 0; i < 32; ++i) {
    int u = i * 256 + t;           // 0..8191
    int c = u >> 7, xx = u & 127;
    tile[c * 130 + xx] = x[((size_t)(b * 64 + c)) * HW + y * 128 + xx];
  }
  __syncthreads();
  const float* mrow = masks + ((size_t)(b * 3 + m)) * HW + y * 128;
  bf16* orow = prow + 7 * 64;
#pragma unroll
  for (int i = 0; i < 32; ++i) {
    int u = i * 256 + t;
    int c = u & 63, xx = u >> 6;
    orow[xx * 64 + c] = (bf16)(tile[c * 130 + xx] * mrow[xx]);
  }
}

// ------- branch convs: wave-autonomous implicit GEMM, 3 blocks/CU ------------
// r10 structure (zero barriers, private dbuf strips) with the strip tightened
// from 48px to 46px (true max span = 31+2d <= 45, i.e. 46 px): LDS drops to
// 52,992 B/block so THREE blocks fit per CU (was 2) -> 12 waves/CU, 3/SIMD,
// +50% TLP to hide per-wave ds_read/VMEM latency (waves are decoupled, so
// TLP applies -- unlike the barrier-lockstep regime where R3 proved it null).
__global__ __launch_bounds__(256, 3) void k_branch(const bf16* __restrict__ xm_p,
                                                   const bf16* __restrict__ kern_t,
                                                   bf16* __restrict__ cat_p) {
  __shared__ bf16 sb[4][2][46 * LPX];   // 4 waves x dbuf x 6,624 B = 52,992 B
  int bid = blockIdx.x;
  int xcd = bid & 7;
  int i   = bid >> 3;          // 0..255
  int b   = xcd >> 1;
  int di  = ((xcd & 1) << 1) | (i & 1);
  int y   = i >> 1;            // 0..127
  int d   = 1 + 2 * di;        // 1,3,5,7
  int t    = threadIdx.x;
  int lane = t & 63;
  int wq   = t >> 6;           // px quarter 0..3
  int lanelo = lane & 15;
  int quad = lane >> 4;

  const bf16* plane0 = xm_p + (size_t)(b * 3) * XM_PLANE;
  const bf16* wb0    = kern_t + (size_t)(b * 27) * 4096 + lane * 8;
  const int gp0 = wq * 32 + 7 - d;     // leftmost staged padded-px of this wave

  bf16* mysb0 = &sb[wq][0][0];
  bf16* mysb1 = &sb[wq][1][0];

  bf16x8 sreg[6];   // 46px x 64ch = 368 chunks of 16B (guard u<368)
  // prologue: phase 0 (m=0,ky=0) -> buf0; issue phase 1 (m=0,ky=1) loads
  {
    const bf16* s0 = plane0 + (size_t)(y + 7 - d) * XM_ROW + gp0 * 64;
#pragma unroll
    for (int r = 0; r < 6; ++r) {
      int u = r * 64 + lane;
      if (u < 368) sreg[r] = *(const bf16x8*)(s0 + u * 8);
    }
#pragma unroll
    for (int r = 0; r < 6; ++r) {
      int u = r * 64 + lane;
      if (u < 368) *(bf16x8*)(mysb0 + (u >> 3) * LPX + (u & 7) * 8) = sreg[r];
    }
    const bf16* s1 = plane0 + (size_t)(y + 7) * XM_ROW + gp0 * 64;
#pragma unroll
    for (int r = 0; r < 6; ++r) {
      int u = r * 64 + lane;
      if (u < 368) sreg[r] = *(const bf16x8*)(s1 + u * 8);
    }
  }

  f32x4 acc[4][2] = {};

#pragma unroll
  for (int p = 0; p < 9; ++p) {
    int m = p / 3, ky = p % 3;
    // A-frags: 3 kx x 2 kci x 4 mt, each one coalesced 1KB wave-load
    bf16x8 areg[3][2][4];
    const bf16* wtap = wb0 + (size_t)(m * 9 + ky * 3) * 4096;
#pragma unroll
    for (int kx = 0; kx < 3; ++kx)
#pragma unroll
      for (int kci = 0; kci < 2; ++kci)
#pragma unroll
        for (int mt = 0; mt < 4; ++mt)
          areg[kx][kci][mt] = *(const bf16x8*)(wtap + kx * 4096 + (mt * 2 + kci) * 512);

    // write phase p+1 (loaded at p-1) into the other private buffer
    if (p < 8) {
      bf16* wbuf = ((p + 1) & 1) ? mysb1 : mysb0;
#pragma unroll
      for (int r = 0; r < 6; ++r) {
        int u = r * 64 + lane;
        if (u < 368) *(bf16x8*)(wbuf + (u >> 3) * LPX + (u & 7) * 8) = sreg[r];
      }
    }
    // issue staging loads for phase p+2
    if (p < 7) {
      int pn = p + 2;
      int mn = pn / 3, kyn = pn % 3;
      const bf16* sn = plane0 + (size_t)mn * XM_PLANE
                     + (size_t)(y + 7 + d * (kyn - 1)) * XM_ROW + gp0 * 64;
#pragma unroll
      for (int r = 0; r < 6; ++r) {
        int u = r * 64 + lane;
        if (u < 368) sreg[r] = *(const bf16x8*)(sn + u * 8);
      }
    }
    // compute from private buf[p&1]; local px = lanelo + d*kx (+ nt*16)
    const bf16* rbuf = (p & 1) ? mysb1 : mysb0;
#pragma unroll
    for (int kx = 0; kx < 3; ++kx) {
      int lpx0 = lanelo + d * kx;
#pragma unroll
      for (int kci = 0; kci < 2; ++kci) {
        bf16x8 bv[2];
#pragma unroll
        for (int nt = 0; nt < 2; ++nt)
          bv[nt] = *(const bf16x8*)(rbuf + (lpx0 + nt * 16) * LPX + quad * 8 + kci * 32);
        __builtin_amdgcn_s_setprio(1);
#pragma unroll
        for (int mt = 0; mt < 4; ++mt)
#pragma unroll
          for (int nt = 0; nt < 2; ++nt)
            acc[mt][nt] = __builtin_amdgcn_mfma_f32_16x16x32_bf16(areg[kx][kci][mt], bv[nt], acc[mt][nt], 0, 0, 0);
        __builtin_amdgcn_s_setprio(0);
      }
    }
  }

  // epilogue: cat_p[b][y+1][px+1][di*64 + oc]
  bf16* cp = cat_p + (size_t)b * CAT_PLANE + (size_t)(y + 1) * CAT_ROW + di * 64;
#pragma unroll
  for (int mt = 0; mt < 4; ++mt) {
#pragma unroll
    for (int nt = 0; nt < 2; ++nt) {
      int px = wq * 32 + nt * 16 + lanelo;
      bf16x4 v;
#pragma unroll
      for (int r = 0; r < 4; ++r) v[r] = (bf16)acc[mt][nt][r];
      *(bf16x4*)(cp + (size_t)(px + 1) * 256 + (mt * 16 + quad * 4)) = v;
    }
  }
}

// ------- final conv + bias + BN + ReLU, v5: wave-autonomous (unchanged) ------
__global__ __launch_bounds__(256, 2) void k_final(const bf16* __restrict__ cat_p,
                                                  const bf16* __restrict__ w2_t,
                                                  const float* __restrict__ cb,
                                                  const float* __restrict__ gamma,
                                                  const float* __restrict__ beta,
                                                  const float* __restrict__ mean,
                                                  const float* __restrict__ var,
                                                  float* __restrict__ out) {
  __shared__ bf16 sb[4][2][40 * LPX];   // 4 waves x dbuf x 5,760 B = 46,080 B
  int bid = blockIdx.x;                 // 0..511
  int xcd = bid & 7;
  int b   = xcd >> 1;
  int y   = ((bid >> 3) << 1) | (xcd & 1);   // 0..127
  int t    = threadIdx.x;
  int lane = t & 63;
  int wq   = t >> 6;           // px quarter 0..3
  int lanelo = lane & 15;
  int quad = lane >> 4;

  const bf16* cb2 = cat_p + (size_t)b * CAT_PLANE + (size_t)(wq * 32) * 256;
  const bf16* wb0 = w2_t + lane * 8;

  bf16* mysb0 = &sb[wq][0][0];
  bf16* mysb1 = &sb[wq][1][0];

  bf16x8 sreg[5];   // 40px x 64ch = 320 chunks of 16B = 5 per lane
  // prologue: phase 0 (cq=0,ky=0) -> buf0; issue phase 1 (cq=0,ky=1) loads
  {
    const bf16* s0 = cb2 + (size_t)y * CAT_ROW;
#pragma unroll
    for (int r = 0; r < 5; ++r) {
      int u = r * 64 + lane;
      sreg[r] = *(const bf16x8*)(s0 + (u >> 3) * 256 + (u & 7) * 8);
    }
#pragma unroll
    for (int r = 0; r < 5; ++r) {
      int u = r * 64 + lane;
      *(bf16x8*)(mysb0 + (u >> 3) * LPX + (u & 7) * 8) = sreg[r];
    }
    const bf16* s1 = cb2 + (size_t)(y + 1) * CAT_ROW;
#pragma unroll
    for (int r = 0; r < 5; ++r) {
      int u = r * 64 + lane;
      sreg[r] = *(const bf16x8*)(s1 + (u >> 3) * 256 + (u & 7) * 8);
    }
  }

  f32x4 acc[4][2] = {};

#pragma unroll
  for (int p = 0; p < 12; ++p) {
    int cq = p / 3, ky = p % 3;
    // A-frags: 3 kx x 2 kci x 4 mt, each one coalesced 1KB wave-load
    bf16x8 areg[3][2][4];
#pragma unroll
    for (int kx = 0; kx < 3; ++kx) {
      const bf16* wt = wb0 + (size_t)(((ky * 3 + kx) * 4 + cq) * 8) * 512;
#pragma unroll
      for (int kci = 0; kci < 2; ++kci)
#pragma unroll
        for (int mt = 0; mt < 4; ++mt)
          areg[kx][kci][mt] = *(const bf16x8*)(wt + (mt * 2 + kci) * 512);
    }

    // write phase p+1 (loaded at p-1) into the other private buffer
    if (p < 11) {
      bf16* wbuf = ((p + 1) & 1) ? mysb1 : mysb0;
#pragma unroll
      for (int r = 0; r < 5; ++r) {
        int u = r * 64 + lane;
        *(bf16x8*)(wbuf + (u >> 3) * LPX + (u & 7) * 8) = sreg[r];
      }
    }
    // issue staging loads for phase p+2
    if (p < 10) {
      int pn = p + 2;
      int cqn = pn / 3, kyn = pn % 3;
      const bf16* sn = cb2 + (size_t)(y + kyn) * CAT_ROW + cqn * 64;
#pragma unroll
      for (int r = 0; r < 5; ++r) {
        int u = r * 64 + lane;
        sreg[r] = *(const bf16x8*)(sn + (u >> 3) * 256 + (u & 7) * 8);
      }
    }
    // compute from private buf[p&1]; local px = lanelo + kx (+ nt*16)
    const bf16* rbuf = (p & 1) ? mysb1 : mysb0;
#pragma unroll
    for (int kx = 0; kx < 3; ++kx) {
      int lpx0 = lanelo + kx;
#pragma unroll
      for (int kci = 0; kci < 2; ++kci) {
        bf16x8 bv[2];
#pragma unroll
        for (int nt = 0; nt < 2; ++nt)
          bv[nt] = *(const bf16x8*)(rbuf + (lpx0 + nt * 16) * LPX + quad * 8 + kci * 32);
        __builtin_amdgcn_s_setprio(1);
#pragma unroll
        for (int mt = 0; mt < 4; ++mt)
#pragma unroll
          for (int nt = 0; nt < 2; ++nt)
            acc[mt][nt] = __builtin_amdgcn_mfma_f32_16x16x32_bf16(areg[kx][kci][mt], bv[nt], acc[mt][nt], 0, 0, 0);
        __builtin_amdgcn_s_setprio(0);
      }
    }
  }

  // epilogue: bias + BN + ReLU -> out[b][oc][y][px]
#pragma unroll
  for (int mt = 0; mt < 4; ++mt) {
#pragma unroll
    for (int nt = 0; nt < 2; ++nt) {
      int px = wq * 32 + nt * 16 + lanelo;
#pragma unroll
      for (int r = 0; r < 4; ++r) {
        int oc = mt * 16 + quad * 4 + r;
        float inv = gamma[oc] * rsqrtf(var[oc] + 1e-5f);
        float v = (acc[mt][nt][r] + cb[oc]) * inv + beta[oc] - mean[oc] * inv;
        out[((size_t)(b * 64 + oc)) * HW + y * 128 + px] = fmaxf(v, 0.0f);
      }
    }
  }
}

extern "C" void kernel_launch(void* const* d_in, const int* in_sizes, int n_in,
                              void* d_out, int out_size, void* d_ws, size_t ws_size,
                              hipStream_t stream) {
  const float* x     = (const float*)d_in[0];
  const float* kern  = (const float*)d_in[1];
  const float* mw    = (const float*)d_in[2];
  const float* mb    = (const float*)d_in[3];
  const float* w2    = (const float*)d_in[4];
  const float* cb    = (const float*)d_in[5];
  const float* gamma = (const float*)d_in[6];
  const float* beta  = (const float*)d_in[7];
  const float* mean  = (const float*)d_in[8];
  const float* var   = (const float*)d_in[9];

  float* out   = (float*)d_out;
  float* masks = out + OUT_ELEMS;

  char* ws = (char*)d_ws;
  bf16* xm_p   = (bf16*)(ws);              // 30,971,904 B
  bf16* cat_p  = (bf16*)(ws + 30971904);   // 34,611,200 B (ends 65,583,104)
  bf16* kern_t = (bf16*)(ws + 65583104);   // 884,736 B
  bf16* w2_t   = (bf16*)(ws + 66467840);   // 294,912 B -> total 66,762,752 B
  // mask partials alias xm_p region (consumed by k_mask2 before k_xmt writes)
  float* part  = (float*)(ws);             // 6,291,456 B < xm_p size

  k_wt<<<2562, 256, 0, stream>>>(kern, w2, kern_t, w2_t, cat_p);
  k_mask1<<<dim3(128, 4, 8), 128, 0, stream>>>(x, mw, part);
  k_mask2<<<dim3(128, 4), 128, 0, stream>>>(part, mb, masks);
  k_xmt<<<dim3(142, 3, 4), 256, 0, stream>>>(x, masks, xm_p);
  k_branch<<<2048, 256, 0, stream>>>(xm_p, kern_t, cat_p);
  k_final<<<512, 256, 0, stream>>>(cat_p, w2_t, cb, gamma, beta, mean, var, out);
}

// Round 13
// 260.061 us; speedup vs baseline: 1.2254x; 1.2254x over previous
//
#include <hip/hip_runtime.h>
#include <math.h>

typedef __bf16 bf16;
typedef __bf16 bf16x8 __attribute__((ext_vector_type(8)));
typedef __bf16 bf16x4 __attribute__((ext_vector_type(4)));
typedef float  f32x4  __attribute__((ext_vector_type(4)));

#define HW        16384      // 128*128
#define OUT_ELEMS 4194304    // 4*64*128*128

// padded xm: [b][m][yp=142][xp=142][c=64], pixel (y,x) at (y+7, x+7)
#define XM_ROW    (142 * 64)
#define XM_PLANE  (142 * XM_ROW)          // 1,290,496 el
// padded cat: [b][yp=130][xp=130][ch=256], pixel (y,x) at (y+1, x+1)
#define CAT_ROW   (130 * 256)
#define CAT_PLANE (130 * CAT_ROW)         // 4,326,400 el

// LDS pixel stride (elements): 64 payload + 8 pad -> 144 B
#define LPX 72

// ------ weight transforms (fp32 -> bf16) + cat_p halo zero -------------------
// kern_t lane-major (r10 layout): kern_t[(bm*9+tap)*4096 + (mt*2+kci)*512 + lane*8 + j]
//   o = mt*16 + (lane&15), c = kci*32 + (lane>>4)*8 + j
// w2_t lane-major layout (same recipe):
//   w2_t[((tap*4 + cq)*8 + mt*2+kci)*512 + lane*8 + j]
//   oc = mt*16 + (lane&15), ch = cq*64 + kci*32 + (lane>>4)*8 + j
__global__ void k_wt(const float* __restrict__ kern, const float* __restrict__ w2,
                     bf16* __restrict__ kern_t, bf16* __restrict__ w2_t,
                     bf16* __restrict__ cat_p) {
  int blk = blockIdx.x;
  if (blk >= 2304) {                      // ---- halo zeroing ----
    int id = (blk - 2304) * 256 + threadIdx.x;
    if (id >= 4 * 16512) return;
    int plane = id / 16512, j = id % 16512;
    bf16* base = cat_p + (size_t)plane * CAT_PLANE;
    bf16x8 zv = {};
    if (j < 8320) {                       // rows 0 and 129, full 130 px
      int row = (j / 4160) * 129;
      int off = (j % 4160) * 8;
      *(bf16x8*)(base + (size_t)row * CAT_ROW + off) = zv;
    } else {                              // rows 1..128, cols 0 and 129
      int k = j - 8320;
      int row = 1 + (k >> 6);
      int idx = k & 63;
      int col = (idx >> 5) * 129;
      int ch8 = (idx & 31) * 8;
      *(bf16x8*)(base + (size_t)row * CAT_ROW + col * 256 + ch8) = zv;
    }
    return;
  }
  int i = blk * 256 + threadIdx.x;
  const int N1 = 4 * 3 * 9 * 64 * 64;   // 442368
  if (i < N1) {
    int j    = i & 7;
    int lane = (i >> 3) & 63;
    int km   = (i >> 9) & 7;            // kci = km&1, mt = km>>1
    int tap  = (i >> 12) % 9;
    int bm   = i / 36864;
    int o = (km >> 1) * 16 + (lane & 15);
    int c = (km & 1) * 32 + (lane >> 4) * 8 + j;
    kern_t[i] = (bf16)kern[(((bm * 64 + o) * 64 + c) * 9) + tap];
  } else {
    int j = i - N1;
    if (j < 64 * 256 * 9) {             // 147,456 el
      int j8   = j & 7;
      int lane = (j >> 3) & 63;
      int km   = (j >> 9) & 7;          // kci = km&1, mt = km>>1
      int cq   = (j >> 12) & 3;
      int tap  = j >> 14;               // 0..8
      int oc = (km >> 1) * 16 + (lane & 15);
      int ch = cq * 64 + (km & 1) * 32 + (lane >> 4) * 8 + j8;
      w2_t[j] = (bf16)w2[(oc * 256 + ch) * 9 + tap];
    }
  }
}

// -------- mask conv stage 1: partial logits over 8-channel groups ------------
__global__ void k_mask1(const float* __restrict__ x, const float* __restrict__ mw,
                        float* __restrict__ part) {
  int y = blockIdx.x, b = blockIdx.y, cg = blockIdx.z;
  int tx = threadIdx.x;      // 0..127
  float a0 = 0.f, a1 = 0.f, a2 = 0.f;
#pragma unroll
  for (int ci = 0; ci < 8; ++ci) {
    int c = cg * 8 + ci;
    const float* xp = x + ((size_t)(b * 64 + c)) * HW;
    const float* w0 = mw + (0 * 64 + c) * 9;
    const float* w1 = mw + (1 * 64 + c) * 9;
    const float* w2 = mw + (2 * 64 + c) * 9;
#pragma unroll
    for (int ky = 0; ky < 3; ++ky) {
      int yy = y + ky - 1;
      if ((unsigned)yy >= 128u) continue;
#pragma unroll
      for (int kx = 0; kx < 3; ++kx) {
        int xx = tx + kx - 1;
        if ((unsigned)xx >= 128u) continue;
        float xv = xp[yy * 128 + xx];
        a0 += xv * w0[ky * 3 + kx];
        a1 += xv * w1[ky * 3 + kx];
        a2 += xv * w2[ky * 3 + kx];
      }
    }
  }
  size_t base = (size_t)((b * 8 + cg) * 3) * HW + y * 128 + tx;
  part[base]          = a0;
  part[base + HW]     = a1;
  part[base + 2 * HW] = a2;
}

// -------- mask conv stage 2: reduce groups + bias + softmax ------------------
__global__ void k_mask2(const float* __restrict__ part, const float* __restrict__ mb,
                        float* __restrict__ masks) {
  int y = blockIdx.x, b = blockIdx.y;
  int tx = threadIdx.x;
  float a0 = mb[0], a1 = mb[1], a2 = mb[2];
  int off = y * 128 + tx;
#pragma unroll
  for (int cg = 0; cg < 8; ++cg) {
    size_t base = (size_t)((b * 8 + cg) * 3) * HW + off;
    a0 += part[base];
    a1 += part[base + HW];
    a2 += part[base + 2 * HW];
  }
  float mx = fmaxf(a0, fmaxf(a1, a2));
  float e0 = __expf(a0 - mx), e1 = __expf(a1 - mx), e2 = __expf(a2 - mx);
  float inv = 1.0f / (e0 + e1 + e2);
  size_t base = ((size_t)b * 3) * HW + off;
  masks[base]          = e0 * inv;
  masks[base + HW]     = e1 * inv;
  masks[base + 2 * HW] = e2 * inv;
}

// -------- xm = x * mask, NCHW fp32 -> padded NHWC(c=64) bf16, incl. halo -----
__global__ void k_xmt(const float* __restrict__ x, const float* __restrict__ masks,
                      bf16* __restrict__ xm_p) {
  int yp = blockIdx.x;  // 0..141 padded row
  int m = blockIdx.y, b = blockIdx.z;
  int t = threadIdx.x;  // 256
  bf16* prow = xm_p + (size_t)(b * 3 + m) * XM_PLANE + (size_t)yp * XM_ROW;
  bf16x8 z = {};
  if (yp < 7 || yp >= 135) {          // full halo row: 142*64/8 = 1136 chunks
#pragma unroll
    for (int i = 0; i < 5; ++i) {
      int u = i * 256 + t;
      if (u < 1136) ((bf16x8*)prow)[u] = z;
    }
    return;
  }
  // side halo: 7 px * 64c = 448 el = 56 chunks each side
  if (t < 56) ((bf16x8*)prow)[t] = z;
  else if (t < 112) ((bf16x8*)(prow + 135 * 64))[t - 56] = z;

  int y = yp - 7;
  __shared__ float tile[64 * 130];
#pragma unroll
  for (int i = 0; i < 32; ++i) {
    int u = i * 256 + t;           // 0..8191
    int c = u >> 7, xx = u & 127;
    tile[c * 130 + xx] = x[((size_t)(b * 64 + c)) * HW + y * 128 + xx];
  }
  __syncthreads();
  const float* mrow = masks + ((size_t)(b * 3 + m)) * HW + y * 128;
  bf16* orow = prow + 7 * 64;
#pragma unroll
  for (int i = 0; i < 32; ++i) {
    int u = i * 256 + t;
    int c = u & 63, xx = u >> 6;
    orow[xx * 64 + c] = (bf16)(tile[c * 130 + xx] * mrow[xx]);
  }
}

// ------- branch convs: wave-autonomous implicit GEMM, 46px strips ------------
// r12 lesson: __launch_bounds__(256,3) capped regs at ~170 < the ~175 this
// kernel needs -> scratch spills (WRITE_SIZE 6x). Keep the 46px strip (LDS
// 52,992 B -> 3 blocks/CU fit) but declare only min-waves=2: the allocator
// stays at ~100 arch VGPRs (no spills) and the RUNTIME occupancy is still
// LDS-limited to 3 blocks/CU = 3 waves/SIMD.
__global__ __launch_bounds__(256, 2) void k_branch(const bf16* __restrict__ xm_p,
                                                   const bf16* __restrict__ kern_t,
                                                   bf16* __restrict__ cat_p) {
  __shared__ bf16 sb[4][2][46 * LPX];   // 4 waves x dbuf x 6,624 B = 52,992 B
  int bid = blockIdx.x;
  int xcd = bid & 7;
  int i   = bid >> 3;          // 0..255
  int b   = xcd >> 1;
  int di  = ((xcd & 1) << 1) | (i & 1);
  int y   = i >> 1;            // 0..127
  int d   = 1 + 2 * di;        // 1,3,5,7
  int t    = threadIdx.x;
  int lane = t & 63;
  int wq   = t >> 6;           // px quarter 0..3
  int lanelo = lane & 15;
  int quad = lane >> 4;

  const bf16* plane0 = xm_p + (size_t)(b * 3) * XM_PLANE;
  const bf16* wb0    = kern_t + (size_t)(b * 27) * 4096 + lane * 8;
  const int gp0 = wq * 32 + 7 - d;     // leftmost staged padded-px of this wave

  bf16* mysb0 = &sb[wq][0][0];
  bf16* mysb1 = &sb[wq][1][0];

  bf16x8 sreg[6];   // 46px x 64ch = 368 chunks of 16B (guard u<368)
  // prologue: phase 0 (m=0,ky=0) -> buf0; issue phase 1 (m=0,ky=1) loads
  {
    const bf16* s0 = plane0 + (size_t)(y + 7 - d) * XM_ROW + gp0 * 64;
#pragma unroll
    for (int r = 0; r < 6; ++r) {
      int u = r * 64 + lane;
      if (u < 368) sreg[r] = *(const bf16x8*)(s0 + u * 8);
    }
#pragma unroll
    for (int r = 0; r < 6; ++r) {
      int u = r * 64 + lane;
      if (u < 368) *(bf16x8*)(mysb0 + (u >> 3) * LPX + (u & 7) * 8) = sreg[r];
    }
    const bf16* s1 = plane0 + (size_t)(y + 7) * XM_ROW + gp0 * 64;
#pragma unroll
    for (int r = 0; r < 6; ++r) {
      int u = r * 64 + lane;
      if (u < 368) sreg[r] = *(const bf16x8*)(s1 + u * 8);
    }
  }

  f32x4 acc[4][2] = {};

#pragma unroll
  for (int p = 0; p < 9; ++p) {
    int m = p / 3, ky = p % 3;
    // A-frags: 3 kx x 2 kci x 4 mt, each one coalesced 1KB wave-load
    bf16x8 areg[3][2][4];
    const bf16* wtap = wb0 + (size_t)(m * 9 + ky * 3) * 4096;
#pragma unroll
    for (int kx = 0; kx < 3; ++kx)
#pragma unroll
      for (int kci = 0; kci < 2; ++kci)
#pragma unroll
        for (int mt = 0; mt < 4; ++mt)
          areg[kx][kci][mt] = *(const bf16x8*)(wtap + kx * 4096 + (mt * 2 + kci) * 512);

    // write phase p+1 (loaded at p-1) into the other private buffer
    if (p < 8) {
      bf16* wbuf = ((p + 1) & 1) ? mysb1 : mysb0;
#pragma unroll
      for (int r = 0; r < 6; ++r) {
        int u = r * 64 + lane;
        if (u < 368) *(bf16x8*)(wbuf + (u >> 3) * LPX + (u & 7) * 8) = sreg[r];
      }
    }
    // issue staging loads for phase p+2
    if (p < 7) {
      int pn = p + 2;
      int mn = pn / 3, kyn = pn % 3;
      const bf16* sn = plane0 + (size_t)mn * XM_PLANE
                     + (size_t)(y + 7 + d * (kyn - 1)) * XM_ROW + gp0 * 64;
#pragma unroll
      for (int r = 0; r < 6; ++r) {
        int u = r * 64 + lane;
        if (u < 368) sreg[r] = *(const bf16x8*)(sn + u * 8);
      }
    }
    // compute from private buf[p&1]; local px = lanelo + d*kx (+ nt*16)
    const bf16* rbuf = (p & 1) ? mysb1 : mysb0;
#pragma unroll
    for (int kx = 0; kx < 3; ++kx) {
      int lpx0 = lanelo + d * kx;
#pragma unroll
      for (int kci = 0; kci < 2; ++kci) {
        bf16x8 bv[2];
#pragma unroll
        for (int nt = 0; nt < 2; ++nt)
          bv[nt] = *(const bf16x8*)(rbuf + (lpx0 + nt * 16) * LPX + quad * 8 + kci * 32);
        __builtin_amdgcn_s_setprio(1);
#pragma unroll
        for (int mt = 0; mt < 4; ++mt)
#pragma unroll
          for (int nt = 0; nt < 2; ++nt)
            acc[mt][nt] = __builtin_amdgcn_mfma_f32_16x16x32_bf16(areg[kx][kci][mt], bv[nt], acc[mt][nt], 0, 0, 0);
        __builtin_amdgcn_s_setprio(0);
      }
    }
  }

  // epilogue: cat_p[b][y+1][px+1][di*64 + oc]
  bf16* cp = cat_p + (size_t)b * CAT_PLANE + (size_t)(y + 1) * CAT_ROW + di * 64;
#pragma unroll
  for (int mt = 0; mt < 4; ++mt) {
#pragma unroll
    for (int nt = 0; nt < 2; ++nt) {
      int px = wq * 32 + nt * 16 + lanelo;
      bf16x4 v;
#pragma unroll
      for (int r = 0; r < 4; ++r) v[r] = (bf16)acc[mt][nt][r];
      *(bf16x4*)(cp + (size_t)(px + 1) * 256 + (mt * 16 + quad * 4)) = v;
    }
  }
}

// ------- final conv + bias + BN + ReLU, v5: wave-autonomous (unchanged) ------
__global__ __launch_bounds__(256, 2) void k_final(const bf16* __restrict__ cat_p,
                                                  const bf16* __restrict__ w2_t,
                                                  const float* __restrict__ cb,
                                                  const float* __restrict__ gamma,
                                                  const float* __restrict__ beta,
                                                  const float* __restrict__ mean,
                                                  const float* __restrict__ var,
                                                  float* __restrict__ out) {
  __shared__ bf16 sb[4][2][40 * LPX];   // 4 waves x dbuf x 5,760 B = 46,080 B
  int bid = blockIdx.x;                 // 0..511
  int xcd = bid & 7;
  int b   = xcd >> 1;
  int y   = ((bid >> 3) << 1) | (xcd & 1);   // 0..127
  int t    = threadIdx.x;
  int lane = t & 63;
  int wq   = t >> 6;           // px quarter 0..3
  int lanelo = lane & 15;
  int quad = lane >> 4;

  const bf16* cb2 = cat_p + (size_t)b * CAT_PLANE + (size_t)(wq * 32) * 256;
  const bf16* wb0 = w2_t + lane * 8;

  bf16* mysb0 = &sb[wq][0][0];
  bf16* mysb1 = &sb[wq][1][0];

  bf16x8 sreg[5];   // 40px x 64ch = 320 chunks of 16B = 5 per lane
  // prologue: phase 0 (cq=0,ky=0) -> buf0; issue phase 1 (cq=0,ky=1) loads
  {
    const bf16* s0 = cb2 + (size_t)y * CAT_ROW;
#pragma unroll
    for (int r = 0; r < 5; ++r) {
      int u = r * 64 + lane;
      sreg[r] = *(const bf16x8*)(s0 + (u >> 3) * 256 + (u & 7) * 8);
    }
#pragma unroll
    for (int r = 0; r < 5; ++r) {
      int u = r * 64 + lane;
      *(bf16x8*)(mysb0 + (u >> 3) * LPX + (u & 7) * 8) = sreg[r];
    }
    const bf16* s1 = cb2 + (size_t)(y + 1) * CAT_ROW;
#pragma unroll
    for (int r = 0; r < 5; ++r) {
      int u = r * 64 + lane;
      sreg[r] = *(const bf16x8*)(s1 + (u >> 3) * 256 + (u & 7) * 8);
    }
  }

  f32x4 acc[4][2] = {};

#pragma unroll
  for (int p = 0; p < 12; ++p) {
    int cq = p / 3, ky = p % 3;
    // A-frags: 3 kx x 2 kci x 4 mt, each one coalesced 1KB wave-load
    bf16x8 areg[3][2][4];
#pragma unroll
    for (int kx = 0; kx < 3; ++kx) {
      const bf16* wt = wb0 + (size_t)(((ky * 3 + kx) * 4 + cq) * 8) * 512;
#pragma unroll
      for (int kci = 0; kci < 2; ++kci)
#pragma unroll
        for (int mt = 0; mt < 4; ++mt)
          areg[kx][kci][mt] = *(const bf16x8*)(wt + (mt * 2 + kci) * 512);
    }

    // write phase p+1 (loaded at p-1) into the other private buffer
    if (p < 11) {
      bf16* wbuf = ((p + 1) & 1) ? mysb1 : mysb0;
#pragma unroll
      for (int r = 0; r < 5; ++r) {
        int u = r * 64 + lane;
        *(bf16x8*)(wbuf + (u >> 3) * LPX + (u & 7) * 8) = sreg[r];
      }
    }
    // issue staging loads for phase p+2
    if (p < 10) {
      int pn = p + 2;
      int cqn = pn / 3, kyn = pn % 3;
      const bf16* sn = cb2 + (size_t)(y + kyn) * CAT_ROW + cqn * 64;
#pragma unroll
      for (int r = 0; r < 5; ++r) {
        int u = r * 64 + lane;
        sreg[r] = *(const bf16x8*)(sn + (u >> 3) * 256 + (u & 7) * 8);
      }
    }
    // compute from private buf[p&1]; local px = lanelo + kx (+ nt*16)
    const bf16* rbuf = (p & 1) ? mysb1 : mysb0;
#pragma unroll
    for (int kx = 0; kx < 3; ++kx) {
      int lpx0 = lanelo + kx;
#pragma unroll
      for (int kci = 0; kci < 2; ++kci) {
        bf16x8 bv[2];
#pragma unroll
        for (int nt = 0; nt < 2; ++nt)
          bv[nt] = *(const bf16x8*)(rbuf + (lpx0 + nt * 16) * LPX + quad * 8 + kci * 32);
        __builtin_amdgcn_s_setprio(1);
#pragma unroll
        for (int mt = 0; mt < 4; ++mt)
#pragma unroll
          for (int nt = 0; nt < 2; ++nt)
            acc[mt][nt] = __builtin_amdgcn_mfma_f32_16x16x32_bf16(areg[kx][kci][mt], bv[nt], acc[mt][nt], 0, 0, 0);
        __builtin_amdgcn_s_setprio(0);
      }
    }
  }

  // epilogue: bias + BN + ReLU -> out[b][oc][y][px]
#pragma unroll
  for (int mt = 0; mt < 4; ++mt) {
#pragma unroll
    for (int nt = 0; nt < 2; ++nt) {
      int px = wq * 32 + nt * 16 + lanelo;
#pragma unroll
      for (int r = 0; r < 4; ++r) {
        int oc = mt * 16 + quad * 4 + r;
        float inv = gamma[oc] * rsqrtf(var[oc] + 1e-5f);
        float v = (acc[mt][nt][r] + cb[oc]) * inv + beta[oc] - mean[oc] * inv;
        out[((size_t)(b * 64 + oc)) * HW + y * 128 + px] = fmaxf(v, 0.0f);
      }
    }
  }
}

extern "C" void kernel_launch(void* const* d_in, const int* in_sizes, int n_in,
                              void* d_out, int out_size, void* d_ws, size_t ws_size,
                              hipStream_t stream) {
  const float* x     = (const float*)d_in[0];
  const float* kern  = (const float*)d_in[1];
  const float* mw    = (const float*)d_in[2];
  const float* mb    = (const float*)d_in[3];
  const float* w2    = (const float*)d_in[4];
  const float* cb    = (const float*)d_in[5];
  const float* gamma = (const float*)d_in[6];
  const float* beta  = (const float*)d_in[7];
  const float* mean  = (const float*)d_in[8];
  const float* var   = (const float*)d_in[9];

  float* out   = (float*)d_out;
  float* masks = out + OUT_ELEMS;

  char* ws = (char*)d_ws;
  bf16* xm_p   = (bf16*)(ws);              // 30,971,904 B
  bf16* cat_p  = (bf16*)(ws + 30971904);   // 34,611,200 B (ends 65,583,104)
  bf16* kern_t = (bf16*)(ws + 65583104);   // 884,736 B
  bf16* w2_t   = (bf16*)(ws + 66467840);   // 294,912 B -> total 66,762,752 B
  // mask partials alias xm_p region (consumed by k_mask2 before k_xmt writes)
  float* part  = (float*)(ws);             // 6,291,456 B < xm_p size

  k_wt<<<2562, 256, 0, stream>>>(kern, w2, kern_t, w2_t, cat_p);
  k_mask1<<<dim3(128, 4, 8), 128, 0, stream>>>(x, mw, part);
  k_mask2<<<dim3(128, 4), 128, 0, stream>>>(part, mb, masks);
  k_xmt<<<dim3(142, 3, 4), 256, 0, stream>>>(x, masks, xm_p);
  k_branch<<<2048, 256, 0, stream>>>(xm_p, kern_t, cat_p);
  k_final<<<512, 256, 0, stream>>>(cat_p, w2_t, cb, gamma, beta, mean, var, out);
}

// Round 15
// 249.560 us; speedup vs baseline: 1.2770x; 1.0421x over previous
//
#include <hip/hip_runtime.h>
#include <math.h>

typedef __bf16 bf16;
typedef __bf16 bf16x8 __attribute__((ext_vector_type(8)));
typedef __bf16 bf16x4 __attribute__((ext_vector_type(4)));
typedef float  f32x4  __attribute__((ext_vector_type(4)));

#define HW        16384      // 128*128
#define OUT_ELEMS 4194304    // 4*64*128*128

// padded xm: [b][m][yp=142][xp=142][c=64], pixel (y,x) at (y+7, x+7)
#define XM_ROW    (142 * 64)
#define XM_PLANE  (142 * XM_ROW)          // 1,290,496 el
// padded cat: [b][yp=130][xp=130][ch=256], pixel (y,x) at (y+1, x+1)
#define CAT_ROW   (130 * 256)
#define CAT_PLANE (130 * CAT_ROW)         // 4,326,400 el

// LDS pixel stride (elements): 64 payload + 8 pad -> 144 B
#define LPX 72

// -------- mask conv stage 1: partial logits over 8-channel groups ------------
__global__ void k_mask1(const float* __restrict__ x, const float* __restrict__ mw,
                        float* __restrict__ part) {
  int y = blockIdx.x, b = blockIdx.y, cg = blockIdx.z;
  int tx = threadIdx.x;      // 0..127
  float a0 = 0.f, a1 = 0.f, a2 = 0.f;
#pragma unroll
  for (int ci = 0; ci < 8; ++ci) {
    int c = cg * 8 + ci;
    const float* xp = x + ((size_t)(b * 64 + c)) * HW;
    const float* w0 = mw + (0 * 64 + c) * 9;
    const float* w1 = mw + (1 * 64 + c) * 9;
    const float* w2 = mw + (2 * 64 + c) * 9;
#pragma unroll
    for (int ky = 0; ky < 3; ++ky) {
      int yy = y + ky - 1;
      if ((unsigned)yy >= 128u) continue;
#pragma unroll
      for (int kx = 0; kx < 3; ++kx) {
        int xx = tx + kx - 1;
        if ((unsigned)xx >= 128u) continue;
        float xv = xp[yy * 128 + xx];
        a0 += xv * w0[ky * 3 + kx];
        a1 += xv * w1[ky * 3 + kx];
        a2 += xv * w2[ky * 3 + kx];
      }
    }
  }
  size_t base = (size_t)((b * 8 + cg) * 3) * HW + y * 128 + tx;
  part[base]          = a0;
  part[base + HW]     = a1;
  part[base + 2 * HW] = a2;
}

// -------- mask conv stage 2: reduce groups + bias + softmax ------------------
__global__ void k_mask2(const float* __restrict__ part, const float* __restrict__ mb,
                        float* __restrict__ masks) {
  int y = blockIdx.x, b = blockIdx.y;
  int tx = threadIdx.x;
  float a0 = mb[0], a1 = mb[1], a2 = mb[2];
  int off = y * 128 + tx;
#pragma unroll
  for (int cg = 0; cg < 8; ++cg) {
    size_t base = (size_t)((b * 8 + cg) * 3) * HW + off;
    a0 += part[base];
    a1 += part[base + HW];
    a2 += part[base + 2 * HW];
  }
  float mx = fmaxf(a0, fmaxf(a1, a2));
  float e0 = __expf(a0 - mx), e1 = __expf(a1 - mx), e2 = __expf(a2 - mx);
  float inv = 1.0f / (e0 + e1 + e2);
  size_t base = ((size_t)b * 3) * HW + off;
  masks[base]          = e0 * inv;
  masks[base + HW]     = e1 * inv;
  masks[base + 2 * HW] = e2 * inv;
}

// -------- xm = x*mask repack + FOLDED weight transform + cat halo zero -------
// Prelude (2-iter grid-stride over 655,872 items): kern_t lane-major, w2_t
// lane-major, cat_p halo zero -- all must finish before k_branch/k_final,
// and xmt precedes both. Saves the separate k_wt launch.
// Main body: NCHW fp32 -> padded NHWC(c=64) bf16. Output repack now uses
// bf16x8 stores (4 iters) instead of 32 scalar bf16 stores (G13).
__global__ void k_xmt(const float* __restrict__ x, const float* __restrict__ masks,
                      bf16* __restrict__ xm_p,
                      const float* __restrict__ kern, const float* __restrict__ w2,
                      bf16* __restrict__ kern_t, bf16* __restrict__ w2_t,
                      bf16* __restrict__ cat_p) {
  int yp = blockIdx.x;  // 0..141 padded row
  int m = blockIdx.y, b = blockIdx.z;
  int t = threadIdx.x;  // 256

  // ---- folded k_wt work: 1704 blocks x 256 thr x 2 iters >= 655,872 items --
  {
    const int NK  = 442368;            // kern_t elements
    const int NW2 = 147456;            // w2_t elements
    const int NH  = 66048;             // halo bf16x8 items (4*16512)
    const int TOT = NK + NW2 + NH;     // 655,872
    int bid2 = yp + 142 * (m + 3 * b); // 0..1703
#pragma unroll
    for (int it = 0; it < 2; ++it) {
      int idx = (bid2 + it * 1704) * 256 + t;
      if (idx < NK) {
        int j    = idx & 7;
        int lane = (idx >> 3) & 63;
        int km   = (idx >> 9) & 7;     // kci = km&1, mt = km>>1
        int tap  = (idx >> 12) % 9;
        int bm   = idx / 36864;
        int o = (km >> 1) * 16 + (lane & 15);
        int c = (km & 1) * 32 + (lane >> 4) * 8 + j;
        kern_t[idx] = (bf16)kern[(((bm * 64 + o) * 64 + c) * 9) + tap];
      } else if (idx < NK + NW2) {
        int j = idx - NK;
        int j8   = j & 7;
        int lane = (j >> 3) & 63;
        int km   = (j >> 9) & 7;
        int cq   = (j >> 12) & 3;
        int tap  = j >> 14;            // 0..8
        int oc = (km >> 1) * 16 + (lane & 15);
        int ch = cq * 64 + (km & 1) * 32 + (lane >> 4) * 8 + j8;
        w2_t[j] = (bf16)w2[(oc * 256 + ch) * 9 + tap];
      } else if (idx < TOT) {
        int id = idx - NK - NW2;       // 0..66047
        int plane = id / 16512, j = id % 16512;
        bf16* base = cat_p + (size_t)plane * CAT_PLANE;
        bf16x8 zv = {};
        if (j < 8320) {                // rows 0 and 129, full 130 px
          int row = (j / 4160) * 129;
          int off = (j % 4160) * 8;
          *(bf16x8*)(base + (size_t)row * CAT_ROW + off) = zv;
        } else {                       // rows 1..128, cols 0 and 129
          int k = j - 8320;
          int row = 1 + (k >> 6);
          int idx2 = k & 63;
          int col = (idx2 >> 5) * 129;
          int ch8 = (idx2 & 31) * 8;
          *(bf16x8*)(base + (size_t)row * CAT_ROW + col * 256 + ch8) = zv;
        }
      }
    }
  }

  bf16* prow = xm_p + (size_t)(b * 3 + m) * XM_PLANE + (size_t)yp * XM_ROW;
  bf16x8 z = {};
  if (yp < 7 || yp >= 135) {          // full halo row: 142*64/8 = 1136 chunks
#pragma unroll
    for (int i = 0; i < 5; ++i) {
      int u = i * 256 + t;
      if (u < 1136) ((bf16x8*)prow)[u] = z;
    }
    return;
  }
  // side halo: 7 px * 64c = 448 el = 56 chunks each side
  if (t < 56) ((bf16x8*)prow)[t] = z;
  else if (t < 112) ((bf16x8*)(prow + 135 * 64))[t - 56] = z;

  int y = yp - 7;
  __shared__ float tile[64 * 130];
#pragma unroll
  for (int i = 0; i < 32; ++i) {
    int u = i * 256 + t;           // 0..8191
    int c = u >> 7, xx = u & 127;
    tile[c * 130 + xx] = x[((size_t)(b * 64 + c)) * HW + y * 128 + xx];
  }
  __syncthreads();
  const float* mrow = masks + ((size_t)(b * 3 + m)) * HW + y * 128;
  bf16* orow = prow + 7 * 64;
  // vectorized repack: thread -> (cg = 8-ch group, xx = pixel); bf16x8 store
#pragma unroll
  for (int i = 0; i < 4; ++i) {
    int u = i * 256 + t;           // 0..1023
    int cg = u & 7, xx = u >> 3;
    float mv = mrow[xx];
    bf16x8 v;
#pragma unroll
    for (int j = 0; j < 8; ++j)
      v[j] = (bf16)(tile[(cg * 8 + j) * 130 + xx] * mv);
    *(bf16x8*)(orow + xx * 64 + cg * 8) = v;
  }
}

// ------- branch convs: wave-autonomous implicit GEMM (r13 best: 91.5us) ------
// Zero barriers, private per-wave dbuf strips (46px), 2048 blocks x 256 thr.
// Occupancy attempts closed: (256,3) spilled (r12), 46px+(256,2) stays at
// 2 blocks/CU for opaque residency reasons (r13) -- keep the proven form.
__global__ __launch_bounds__(256, 2) void k_branch(const bf16* __restrict__ xm_p,
                                                   const bf16* __restrict__ kern_t,
                                                   bf16* __restrict__ cat_p) {
  __shared__ bf16 sb[4][2][46 * LPX];   // 4 waves x dbuf x 6,624 B = 52,992 B
  int bid = blockIdx.x;
  int xcd = bid & 7;
  int i   = bid >> 3;          // 0..255
  int b   = xcd >> 1;
  int di  = ((xcd & 1) << 1) | (i & 1);
  int y   = i >> 1;            // 0..127
  int d   = 1 + 2 * di;        // 1,3,5,7
  int t    = threadIdx.x;
  int lane = t & 63;
  int wq   = t >> 6;           // px quarter 0..3
  int lanelo = lane & 15;
  int quad = lane >> 4;

  const bf16* plane0 = xm_p + (size_t)(b * 3) * XM_PLANE;
  const bf16* wb0    = kern_t + (size_t)(b * 27) * 4096 + lane * 8;
  const int gp0 = wq * 32 + 7 - d;     // leftmost staged padded-px of this wave

  bf16* mysb0 = &sb[wq][0][0];
  bf16* mysb1 = &sb[wq][1][0];

  bf16x8 sreg[6];   // 46px x 64ch = 368 chunks of 16B (guard u<368)
  // prologue: phase 0 (m=0,ky=0) -> buf0; issue phase 1 (m=0,ky=1) loads
  {
    const bf16* s0 = plane0 + (size_t)(y + 7 - d) * XM_ROW + gp0 * 64;
#pragma unroll
    for (int r = 0; r < 6; ++r) {
      int u = r * 64 + lane;
      if (u < 368) sreg[r] = *(const bf16x8*)(s0 + u * 8);
    }
#pragma unroll
    for (int r = 0; r < 6; ++r) {
      int u = r * 64 + lane;
      if (u < 368) *(bf16x8*)(mysb0 + (u >> 3) * LPX + (u & 7) * 8) = sreg[r];
    }
    const bf16* s1 = plane0 + (size_t)(y + 7) * XM_ROW + gp0 * 64;
#pragma unroll
    for (int r = 0; r < 6; ++r) {
      int u = r * 64 + lane;
      if (u < 368) sreg[r] = *(const bf16x8*)(s1 + u * 8);
    }
  }

  f32x4 acc[4][2] = {};

#pragma unroll
  for (int p = 0; p < 9; ++p) {
    int m = p / 3, ky = p % 3;
    // A-frags: 3 kx x 2 kci x 4 mt, each one coalesced 1KB wave-load
    bf16x8 areg[3][2][4];
    const bf16* wtap = wb0 + (size_t)(m * 9 + ky * 3) * 4096;
#pragma unroll
    for (int kx = 0; kx < 3; ++kx)
#pragma unroll
      for (int kci = 0; kci < 2; ++kci)
#pragma unroll
        for (int mt = 0; mt < 4; ++mt)
          areg[kx][kci][mt] = *(const bf16x8*)(wtap + kx * 4096 + (mt * 2 + kci) * 512);

    // write phase p+1 (loaded at p-1) into the other private buffer
    if (p < 8) {
      bf16* wbuf = ((p + 1) & 1) ? mysb1 : mysb0;
#pragma unroll
      for (int r = 0; r < 6; ++r) {
        int u = r * 64 + lane;
        if (u < 368) *(bf16x8*)(wbuf + (u >> 3) * LPX + (u & 7) * 8) = sreg[r];
      }
    }
    // issue staging loads for phase p+2
    if (p < 7) {
      int pn = p + 2;
      int mn = pn / 3, kyn = pn % 3;
      const bf16* sn = plane0 + (size_t)mn * XM_PLANE
                     + (size_t)(y + 7 + d * (kyn - 1)) * XM_ROW + gp0 * 64;
#pragma unroll
      for (int r = 0; r < 6; ++r) {
        int u = r * 64 + lane;
        if (u < 368) sreg[r] = *(const bf16x8*)(sn + u * 8);
      }
    }
    // compute from private buf[p&1]; local px = lanelo + d*kx (+ nt*16)
    const bf16* rbuf = (p & 1) ? mysb1 : mysb0;
#pragma unroll
    for (int kx = 0; kx < 3; ++kx) {
      int lpx0 = lanelo + d * kx;
#pragma unroll
      for (int kci = 0; kci < 2; ++kci) {
        bf16x8 bv[2];
#pragma unroll
        for (int nt = 0; nt < 2; ++nt)
          bv[nt] = *(const bf16x8*)(rbuf + (lpx0 + nt * 16) * LPX + quad * 8 + kci * 32);
        __builtin_amdgcn_s_setprio(1);
#pragma unroll
        for (int mt = 0; mt < 4; ++mt)
#pragma unroll
          for (int nt = 0; nt < 2; ++nt)
            acc[mt][nt] = __builtin_amdgcn_mfma_f32_16x16x32_bf16(areg[kx][kci][mt], bv[nt], acc[mt][nt], 0, 0, 0);
        __builtin_amdgcn_s_setprio(0);
      }
    }
  }

  // epilogue: cat_p[b][y+1][px+1][di*64 + oc]
  bf16* cp = cat_p + (size_t)b * CAT_PLANE + (size_t)(y + 1) * CAT_ROW + di * 64;
#pragma unroll
  for (int mt = 0; mt < 4; ++mt) {
#pragma unroll
    for (int nt = 0; nt < 2; ++nt) {
      int px = wq * 32 + nt * 16 + lanelo;
      bf16x4 v;
#pragma unroll
      for (int r = 0; r < 4; ++r) v[r] = (bf16)acc[mt][nt][r];
      *(bf16x4*)(cp + (size_t)(px + 1) * 256 + (mt * 16 + quad * 4)) = v;
    }
  }
}

// ------- final conv + bias + BN + ReLU, v5: wave-autonomous (unchanged) ------
__global__ __launch_bounds__(256, 2) void k_final(const bf16* __restrict__ cat_p,
                                                  const bf16* __restrict__ w2_t,
                                                  const float* __restrict__ cb,
                                                  const float* __restrict__ gamma,
                                                  const float* __restrict__ beta,
                                                  const float* __restrict__ mean,
                                                  const float* __restrict__ var,
                                                  float* __restrict__ out) {
  __shared__ bf16 sb[4][2][40 * LPX];   // 4 waves x dbuf x 5,760 B = 46,080 B
  int bid = blockIdx.x;                 // 0..511
  int xcd = bid & 7;
  int b   = xcd >> 1;
  int y   = ((bid >> 3) << 1) | (xcd & 1);   // 0..127
  int t    = threadIdx.x;
  int lane = t & 63;
  int wq   = t >> 6;           // px quarter 0..3
  int lanelo = lane & 15;
  int quad = lane >> 4;

  const bf16* cb2 = cat_p + (size_t)b * CAT_PLANE + (size_t)(wq * 32) * 256;
  const bf16* wb0 = w2_t + lane * 8;

  bf16* mysb0 = &sb[wq][0][0];
  bf16* mysb1 = &sb[wq][1][0];

  bf16x8 sreg[5];   // 40px x 64ch = 320 chunks of 16B = 5 per lane
  // prologue: phase 0 (cq=0,ky=0) -> buf0; issue phase 1 (cq=0,ky=1) loads
  {
    const bf16* s0 = cb2 + (size_t)y * CAT_ROW;
#pragma unroll
    for (int r = 0; r < 5; ++r) {
      int u = r * 64 + lane;
      sreg[r] = *(const bf16x8*)(s0 + (u >> 3) * 256 + (u & 7) * 8);
    }
#pragma unroll
    for (int r = 0; r < 5; ++r) {
      int u = r * 64 + lane;
      *(bf16x8*)(mysb0 + (u >> 3) * LPX + (u & 7) * 8) = sreg[r];
    }
    const bf16* s1 = cb2 + (size_t)(y + 1) * CAT_ROW;
#pragma unroll
    for (int r = 0; r < 5; ++r) {
      int u = r * 64 + lane;
      sreg[r] = *(const bf16x8*)(s1 + (u >> 3) * 256 + (u & 7) * 8);
    }
  }

  f32x4 acc[4][2] = {};

#pragma unroll
  for (int p = 0; p < 12; ++p) {
    int cq = p / 3, ky = p % 3;
    // A-frags: 3 kx x 2 kci x 4 mt, each one coalesced 1KB wave-load
    bf16x8 areg[3][2][4];
#pragma unroll
    for (int kx = 0; kx < 3; ++kx) {
      const bf16* wt = wb0 + (size_t)(((ky * 3 + kx) * 4 + cq) * 8) * 512;
#pragma unroll
      for (int kci = 0; kci < 2; ++kci)
#pragma unroll
        for (int mt = 0; mt < 4; ++mt)
          areg[kx][kci][mt] = *(const bf16x8*)(wt + (mt * 2 + kci) * 512);
    }

    // write phase p+1 (loaded at p-1) into the other private buffer
    if (p < 11) {
      bf16* wbuf = ((p + 1) & 1) ? mysb1 : mysb0;
#pragma unroll
      for (int r = 0; r < 5; ++r) {
        int u = r * 64 + lane;
        *(bf16x8*)(wbuf + (u >> 3) * LPX + (u & 7) * 8) = sreg[r];
      }
    }
    // issue staging loads for phase p+2
    if (p < 10) {
      int pn = p + 2;
      int cqn = pn / 3, kyn = pn % 3;
      const bf16* sn = cb2 + (size_t)(y + kyn) * CAT_ROW + cqn * 64;
#pragma unroll
      for (int r = 0; r < 5; ++r) {
        int u = r * 64 + lane;
        sreg[r] = *(const bf16x8*)(sn + (u >> 3) * 256 + (u & 7) * 8);
      }
    }
    // compute from private buf[p&1]; local px = lanelo + kx (+ nt*16)
    const bf16* rbuf = (p & 1) ? mysb1 : mysb0;
#pragma unroll
    for (int kx = 0; kx < 3; ++kx) {
      int lpx0 = lanelo + kx;
#pragma unroll
      for (int kci = 0; kci < 2; ++kci) {
        bf16x8 bv[2];
#pragma unroll
        for (int nt = 0; nt < 2; ++nt)
          bv[nt] = *(const bf16x8*)(rbuf + (lpx0 + nt * 16) * LPX + quad * 8 + kci * 32);
        __builtin_amdgcn_s_setprio(1);
#pragma unroll
        for (int mt = 0; mt < 4; ++mt)
#pragma unroll
          for (int nt = 0; nt < 2; ++nt)
            acc[mt][nt] = __builtin_amdgcn_mfma_f32_16x16x32_bf16(areg[kx][kci][mt], bv[nt], acc[mt][nt], 0, 0, 0);
        __builtin_amdgcn_s_setprio(0);
      }
    }
  }

  // epilogue: bias + BN + ReLU -> out[b][oc][y][px]
#pragma unroll
  for (int mt = 0; mt < 4; ++mt) {
#pragma unroll
    for (int nt = 0; nt < 2; ++nt) {
      int px = wq * 32 + nt * 16 + lanelo;
#pragma unroll
      for (int r = 0; r < 4; ++r) {
        int oc = mt * 16 + quad * 4 + r;
        float inv = gamma[oc] * rsqrtf(var[oc] + 1e-5f);
        float v = (acc[mt][nt][r] + cb[oc]) * inv + beta[oc] - mean[oc] * inv;
        out[((size_t)(b * 64 + oc)) * HW + y * 128 + px] = fmaxf(v, 0.0f);
      }
    }
  }
}

extern "C" void kernel_launch(void* const* d_in, const int* in_sizes, int n_in,
                              void* d_out, int out_size, void* d_ws, size_t ws_size,
                              hipStream_t stream) {
  const float* x     = (const float*)d_in[0];
  const float* kern  = (const float*)d_in[1];
  const float* mw    = (const float*)d_in[2];
  const float* mb    = (const float*)d_in[3];
  const float* w2    = (const float*)d_in[4];
  const float* cb    = (const float*)d_in[5];
  const float* gamma = (const float*)d_in[6];
  const float* beta  = (const float*)d_in[7];
  const float* mean  = (const float*)d_in[8];
  const float* var   = (const float*)d_in[9];

  float* out   = (float*)d_out;
  float* masks = out + OUT_ELEMS;

  char* ws = (char*)d_ws;
  bf16* xm_p   = (bf16*)(ws);              // 30,971,904 B
  bf16* cat_p  = (bf16*)(ws + 30971904);   // 34,611,200 B (ends 65,583,104)
  bf16* kern_t = (bf16*)(ws + 65583104);   // 884,736 B
  bf16* w2_t   = (bf16*)(ws + 66467840);   // 294,912 B -> total 66,762,752 B
  // mask partials alias xm_p region (consumed by k_mask2 before k_xmt writes)
  float* part  = (float*)(ws);             // 6,291,456 B < xm_p size

  k_mask1<<<dim3(128, 4, 8), 128, 0, stream>>>(x, mw, part);
  k_mask2<<<dim3(128, 4), 128, 0, stream>>>(part, mb, masks);
  k_xmt<<<dim3(142, 3, 4), 256, 0, stream>>>(x, masks, xm_p, kern, w2, kern_t, w2_t, cat_p);
  k_branch<<<2048, 256, 0, stream>>>(xm_p, kern_t, cat_p);
  k_final<<<512, 256, 0, stream>>>(cat_p, w2_t, cb, gamma, beta, mean, var, out);
}

// Round 16
// 236.260 us; speedup vs baseline: 1.3489x; 1.0563x over previous
//
#include <hip/hip_runtime.h>
#include <math.h>

typedef __bf16 bf16;
typedef __bf16 bf16x8 __attribute__((ext_vector_type(8)));
typedef __bf16 bf16x4 __attribute__((ext_vector_type(4)));
typedef float  f32x4  __attribute__((ext_vector_type(4)));

#define HW        16384      // 128*128
#define OUT_ELEMS 4194304    // 4*64*128*128

// padded xm: [b][m][yp=142][xp=142][c=64], pixel (y,x) at (y+7, x+7)
#define XM_ROW    (142 * 64)
#define XM_PLANE  (142 * XM_ROW)          // 1,290,496 el
// padded cat: [b][yp=130][xp=130][ch=256], pixel (y,x) at (y+1, x+1)
#define CAT_ROW   (130 * 256)
#define CAT_PLANE (130 * CAT_ROW)         // 4,326,400 el

// LDS pixel stride (elements): 64 payload + 8 pad -> 144 B
#define LPX 72

// -------- mask conv stage 1: partial logits over 8-channel groups ------------
// part now aliases the cat_p region (dead before k_branch writes cat_p).
__global__ void k_mask1(const float* __restrict__ x, const float* __restrict__ mw,
                        float* __restrict__ part) {
  int y = blockIdx.x, b = blockIdx.y, cg = blockIdx.z;
  int tx = threadIdx.x;      // 0..127
  float a0 = 0.f, a1 = 0.f, a2 = 0.f;
#pragma unroll
  for (int ci = 0; ci < 8; ++ci) {
    int c = cg * 8 + ci;
    const float* xp = x + ((size_t)(b * 64 + c)) * HW;
    const float* w0 = mw + (0 * 64 + c) * 9;
    const float* w1 = mw + (1 * 64 + c) * 9;
    const float* w2 = mw + (2 * 64 + c) * 9;
#pragma unroll
    for (int ky = 0; ky < 3; ++ky) {
      int yy = y + ky - 1;
      if ((unsigned)yy >= 128u) continue;
#pragma unroll
      for (int kx = 0; kx < 3; ++kx) {
        int xx = tx + kx - 1;
        if ((unsigned)xx >= 128u) continue;
        float xv = xp[yy * 128 + xx];
        a0 += xv * w0[ky * 3 + kx];
        a1 += xv * w1[ky * 3 + kx];
        a2 += xv * w2[ky * 3 + kx];
      }
    }
  }
  size_t base = (size_t)((b * 8 + cg) * 3) * HW + y * 128 + tx;
  part[base]          = a0;
  part[base + HW]     = a1;
  part[base + 2 * HW] = a2;
}

// -------- xm repack + FOLDED weight transforms + FOLDED mask softmax ---------
// Prelude (2-iter grid-stride, 589,824 items): kern_t + w2_t lane-major.
// Main body: each non-halo block computes its OWN mask row from part
// (bias + softmax over m, tx<128), shares via LDS; m==0 blocks write the
// masks output. Then x*mask -> padded NHWC bf16 with bf16x8 stores.
// Removes the k_mask2 launch + its RAW gap.
__global__ void k_xmt(const float* __restrict__ x, const float* __restrict__ part,
                      const float* __restrict__ mb, float* __restrict__ masks,
                      bf16* __restrict__ xm_p,
                      const float* __restrict__ kern, const float* __restrict__ w2,
                      bf16* __restrict__ kern_t, bf16* __restrict__ w2_t) {
  int yp = blockIdx.x;  // 0..141 padded row
  int m = blockIdx.y, b = blockIdx.z;
  int t = threadIdx.x;  // 256

  // ---- folded weight transforms: 1704 blocks x 256 thr x 2 iters -----------
  {
    const int NK  = 442368;            // kern_t elements
    const int NW2 = 147456;            // w2_t elements
    int bid2 = yp + 142 * (m + 3 * b); // 0..1703
#pragma unroll
    for (int it = 0; it < 2; ++it) {
      int idx = (bid2 + it * 1704) * 256 + t;
      if (idx < NK) {
        int j    = idx & 7;
        int lane = (idx >> 3) & 63;
        int km   = (idx >> 9) & 7;     // kci = km&1, mt = km>>1
        int tap  = (idx >> 12) % 9;
        int bm   = idx / 36864;
        int o = (km >> 1) * 16 + (lane & 15);
        int c = (km & 1) * 32 + (lane >> 4) * 8 + j;
        kern_t[idx] = (bf16)kern[(((bm * 64 + o) * 64 + c) * 9) + tap];
      } else if (idx < NK + NW2) {
        int j = idx - NK;
        int j8   = j & 7;
        int lane = (j >> 3) & 63;
        int km   = (j >> 9) & 7;
        int cq   = (j >> 12) & 3;
        int tap  = j >> 14;            // 0..8
        int oc = (km >> 1) * 16 + (lane & 15);
        int ch = cq * 64 + (km & 1) * 32 + (lane >> 4) * 8 + j8;
        w2_t[j] = (bf16)w2[(oc * 256 + ch) * 9 + tap];
      }
    }
  }

  bf16* prow = xm_p + (size_t)(b * 3 + m) * XM_PLANE + (size_t)yp * XM_ROW;
  bf16x8 z = {};
  if (yp < 7 || yp >= 135) {          // full halo row: 142*64/8 = 1136 chunks
#pragma unroll
    for (int i = 0; i < 5; ++i) {
      int u = i * 256 + t;
      if (u < 1136) ((bf16x8*)prow)[u] = z;
    }
    return;
  }
  // side halo: 7 px * 64c = 448 el = 56 chunks each side
  if (t < 56) ((bf16x8*)prow)[t] = z;
  else if (t < 112) ((bf16x8*)(prow + 135 * 64))[t - 56] = z;

  int y = yp - 7;
  __shared__ float tile[64 * 130];
  __shared__ float mrow_s[128];
#pragma unroll
  for (int i = 0; i < 32; ++i) {
    int u = i * 256 + t;           // 0..8191
    int c = u >> 7, xx = u & 127;
    tile[c * 130 + xx] = x[((size_t)(b * 64 + c)) * HW + y * 128 + xx];
  }
  // folded mask softmax: reduce 8 groups + bias + softmax (tx<128)
  if (t < 128) {
    float a0 = mb[0], a1 = mb[1], a2 = mb[2];
    int off = y * 128 + t;
#pragma unroll
    for (int cg = 0; cg < 8; ++cg) {
      size_t base = (size_t)((b * 8 + cg) * 3) * HW + off;
      a0 += part[base];
      a1 += part[base + HW];
      a2 += part[base + 2 * HW];
    }
    float mx = fmaxf(a0, fmaxf(a1, a2));
    float e0 = __expf(a0 - mx), e1 = __expf(a1 - mx), e2 = __expf(a2 - mx);
    float inv = 1.0f / (e0 + e1 + e2);
    float v0 = e0 * inv, v1 = e1 * inv, v2 = e2 * inv;
    mrow_s[t] = (m == 0) ? v0 : (m == 1) ? v1 : v2;
    if (m == 0) {                       // one writer per (y,b): all 3 rows
      size_t mbase = ((size_t)b * 3) * HW + off;
      masks[mbase]          = v0;
      masks[mbase + HW]     = v1;
      masks[mbase + 2 * HW] = v2;
    }
  }
  __syncthreads();
  bf16* orow = prow + 7 * 64;
  // vectorized repack: thread -> (cg = 8-ch group, xx = pixel); bf16x8 store
#pragma unroll
  for (int i = 0; i < 4; ++i) {
    int u = i * 256 + t;           // 0..1023
    int cg = u & 7, xx = u >> 3;
    float mv = mrow_s[xx];
    bf16x8 v;
#pragma unroll
    for (int j = 0; j < 8; ++j)
      v[j] = (bf16)(tile[(cg * 8 + j) * 130 + xx] * mv);
    *(bf16x8*)(orow + xx * 64 + cg * 8) = v;
  }
}

// ------- branch convs: wave-autonomous implicit GEMM + FOLDED cat halo zero --
// Main loop identical to the proven r13 form (92-98us band). Prelude: blocks
// 0..257 zero the cat_p halo (1 bf16x8 store/thread, 66,048 items exactly) --
// must run in k_branch (not earlier) because part aliases cat_p until xmt.
__global__ __launch_bounds__(256, 2) void k_branch(const bf16* __restrict__ xm_p,
                                                   const bf16* __restrict__ kern_t,
                                                   bf16* __restrict__ cat_p) {
  __shared__ bf16 sb[4][2][46 * LPX];   // 4 waves x dbuf x 6,624 B = 52,992 B
  int bid = blockIdx.x;
  // ---- folded halo zeroing: 258 blocks x 256 thr = 66,048 items ------------
  {
    int id = bid * 256 + threadIdx.x;
    if (id < 4 * 16512) {
      int plane = id / 16512, j = id % 16512;
      bf16* base = cat_p + (size_t)plane * CAT_PLANE;
      bf16x8 zv = {};
      if (j < 8320) {                   // rows 0 and 129, full 130 px
        int row = (j / 4160) * 129;
        int off = (j % 4160) * 8;
        *(bf16x8*)(base + (size_t)row * CAT_ROW + off) = zv;
      } else {                          // rows 1..128, cols 0 and 129
        int k = j - 8320;
        int row = 1 + (k >> 6);
        int idx2 = k & 63;
        int col = (idx2 >> 5) * 129;
        int ch8 = (idx2 & 31) * 8;
        *(bf16x8*)(base + (size_t)row * CAT_ROW + col * 256 + ch8) = zv;
      }
    }
  }
  int xcd = bid & 7;
  int i   = bid >> 3;          // 0..255
  int b   = xcd >> 1;
  int di  = ((xcd & 1) << 1) | (i & 1);
  int y   = i >> 1;            // 0..127
  int d   = 1 + 2 * di;        // 1,3,5,7
  int t    = threadIdx.x;
  int lane = t & 63;
  int wq   = t >> 6;           // px quarter 0..3
  int lanelo = lane & 15;
  int quad = lane >> 4;

  const bf16* plane0 = xm_p + (size_t)(b * 3) * XM_PLANE;
  const bf16* wb0    = kern_t + (size_t)(b * 27) * 4096 + lane * 8;
  const int gp0 = wq * 32 + 7 - d;     // leftmost staged padded-px of this wave

  bf16* mysb0 = &sb[wq][0][0];
  bf16* mysb1 = &sb[wq][1][0];

  bf16x8 sreg[6];   // 46px x 64ch = 368 chunks of 16B (guard u<368)
  // prologue: phase 0 (m=0,ky=0) -> buf0; issue phase 1 (m=0,ky=1) loads
  {
    const bf16* s0 = plane0 + (size_t)(y + 7 - d) * XM_ROW + gp0 * 64;
#pragma unroll
    for (int r = 0; r < 6; ++r) {
      int u = r * 64 + lane;
      if (u < 368) sreg[r] = *(const bf16x8*)(s0 + u * 8);
    }
#pragma unroll
    for (int r = 0; r < 6; ++r) {
      int u = r * 64 + lane;
      if (u < 368) *(bf16x8*)(mysb0 + (u >> 3) * LPX + (u & 7) * 8) = sreg[r];
    }
    const bf16* s1 = plane0 + (size_t)(y + 7) * XM_ROW + gp0 * 64;
#pragma unroll
    for (int r = 0; r < 6; ++r) {
      int u = r * 64 + lane;
      if (u < 368) sreg[r] = *(const bf16x8*)(s1 + u * 8);
    }
  }

  f32x4 acc[4][2] = {};

#pragma unroll
  for (int p = 0; p < 9; ++p) {
    int m = p / 3, ky = p % 3;
    // A-frags: 3 kx x 2 kci x 4 mt, each one coalesced 1KB wave-load
    bf16x8 areg[3][2][4];
    const bf16* wtap = wb0 + (size_t)(m * 9 + ky * 3) * 4096;
#pragma unroll
    for (int kx = 0; kx < 3; ++kx)
#pragma unroll
      for (int kci = 0; kci < 2; ++kci)
#pragma unroll
        for (int mt = 0; mt < 4; ++mt)
          areg[kx][kci][mt] = *(const bf16x8*)(wtap + kx * 4096 + (mt * 2 + kci) * 512);

    // write phase p+1 (loaded at p-1) into the other private buffer
    if (p < 8) {
      bf16* wbuf = ((p + 1) & 1) ? mysb1 : mysb0;
#pragma unroll
      for (int r = 0; r < 6; ++r) {
        int u = r * 64 + lane;
        if (u < 368) *(bf16x8*)(wbuf + (u >> 3) * LPX + (u & 7) * 8) = sreg[r];
      }
    }
    // issue staging loads for phase p+2
    if (p < 7) {
      int pn = p + 2;
      int mn = pn / 3, kyn = pn % 3;
      const bf16* sn = plane0 + (size_t)mn * XM_PLANE
                     + (size_t)(y + 7 + d * (kyn - 1)) * XM_ROW + gp0 * 64;
#pragma unroll
      for (int r = 0; r < 6; ++r) {
        int u = r * 64 + lane;
        if (u < 368) sreg[r] = *(const bf16x8*)(sn + u * 8);
      }
    }
    // compute from private buf[p&1]; local px = lanelo + d*kx (+ nt*16)
    const bf16* rbuf = (p & 1) ? mysb1 : mysb0;
#pragma unroll
    for (int kx = 0; kx < 3; ++kx) {
      int lpx0 = lanelo + d * kx;
#pragma unroll
      for (int kci = 0; kci < 2; ++kci) {
        bf16x8 bv[2];
#pragma unroll
        for (int nt = 0; nt < 2; ++nt)
          bv[nt] = *(const bf16x8*)(rbuf + (lpx0 + nt * 16) * LPX + quad * 8 + kci * 32);
        __builtin_amdgcn_s_setprio(1);
#pragma unroll
        for (int mt = 0; mt < 4; ++mt)
#pragma unroll
          for (int nt = 0; nt < 2; ++nt)
            acc[mt][nt] = __builtin_amdgcn_mfma_f32_16x16x32_bf16(areg[kx][kci][mt], bv[nt], acc[mt][nt], 0, 0, 0);
        __builtin_amdgcn_s_setprio(0);
      }
    }
  }

  // epilogue: cat_p[b][y+1][px+1][di*64 + oc]
  bf16* cp = cat_p + (size_t)b * CAT_PLANE + (size_t)(y + 1) * CAT_ROW + di * 64;
#pragma unroll
  for (int mt = 0; mt < 4; ++mt) {
#pragma unroll
    for (int nt = 0; nt < 2; ++nt) {
      int px = wq * 32 + nt * 16 + lanelo;
      bf16x4 v;
#pragma unroll
      for (int r = 0; r < 4; ++r) v[r] = (bf16)acc[mt][nt][r];
      *(bf16x4*)(cp + (size_t)(px + 1) * 256 + (mt * 16 + quad * 4)) = v;
    }
  }
}

// ------- final conv + bias + BN + ReLU, v5: wave-autonomous (unchanged) ------
__global__ __launch_bounds__(256, 2) void k_final(const bf16* __restrict__ cat_p,
                                                  const bf16* __restrict__ w2_t,
                                                  const float* __restrict__ cb,
                                                  const float* __restrict__ gamma,
                                                  const float* __restrict__ beta,
                                                  const float* __restrict__ mean,
                                                  const float* __restrict__ var,
                                                  float* __restrict__ out) {
  __shared__ bf16 sb[4][2][40 * LPX];   // 4 waves x dbuf x 5,760 B = 46,080 B
  int bid = blockIdx.x;                 // 0..511
  int xcd = bid & 7;
  int b   = xcd >> 1;
  int y   = ((bid >> 3) << 1) | (xcd & 1);   // 0..127
  int t    = threadIdx.x;
  int lane = t & 63;
  int wq   = t >> 6;           // px quarter 0..3
  int lanelo = lane & 15;
  int quad = lane >> 4;

  const bf16* cb2 = cat_p + (size_t)b * CAT_PLANE + (size_t)(wq * 32) * 256;
  const bf16* wb0 = w2_t + lane * 8;

  bf16* mysb0 = &sb[wq][0][0];
  bf16* mysb1 = &sb[wq][1][0];

  bf16x8 sreg[5];   // 40px x 64ch = 320 chunks of 16B = 5 per lane
  // prologue: phase 0 (cq=0,ky=0) -> buf0; issue phase 1 (cq=0,ky=1) loads
  {
    const bf16* s0 = cb2 + (size_t)y * CAT_ROW;
#pragma unroll
    for (int r = 0; r < 5; ++r) {
      int u = r * 64 + lane;
      sreg[r] = *(const bf16x8*)(s0 + (u >> 3) * 256 + (u & 7) * 8);
    }
#pragma unroll
    for (int r = 0; r < 5; ++r) {
      int u = r * 64 + lane;
      *(bf16x8*)(mysb0 + (u >> 3) * LPX + (u & 7) * 8) = sreg[r];
    }
    const bf16* s1 = cb2 + (size_t)(y + 1) * CAT_ROW;
#pragma unroll
    for (int r = 0; r < 5; ++r) {
      int u = r * 64 + lane;
      sreg[r] = *(const bf16x8*)(s1 + (u >> 3) * 256 + (u & 7) * 8);
    }
  }

  f32x4 acc[4][2] = {};

#pragma unroll
  for (int p = 0; p < 12; ++p) {
    int cq = p / 3, ky = p % 3;
    // A-frags: 3 kx x 2 kci x 4 mt, each one coalesced 1KB wave-load
    bf16x8 areg[3][2][4];
#pragma unroll
    for (int kx = 0; kx < 3; ++kx) {
      const bf16* wt = wb0 + (size_t)(((ky * 3 + kx) * 4 + cq) * 8) * 512;
#pragma unroll
      for (int kci = 0; kci < 2; ++kci)
#pragma unroll
        for (int mt = 0; mt < 4; ++mt)
          areg[kx][kci][mt] = *(const bf16x8*)(wt + (mt * 2 + kci) * 512);
    }

    // write phase p+1 (loaded at p-1) into the other private buffer
    if (p < 11) {
      bf16* wbuf = ((p + 1) & 1) ? mysb1 : mysb0;
#pragma unroll
      for (int r = 0; r < 5; ++r) {
        int u = r * 64 + lane;
        *(bf16x8*)(wbuf + (u >> 3) * LPX + (u & 7) * 8) = sreg[r];
      }
    }
    // issue staging loads for phase p+2
    if (p < 10) {
      int pn = p + 2;
      int cqn = pn / 3, kyn = pn % 3;
      const bf16* sn = cb2 + (size_t)(y + kyn) * CAT_ROW + cqn * 64;
#pragma unroll
      for (int r = 0; r < 5; ++r) {
        int u = r * 64 + lane;
        sreg[r] = *(const bf16x8*)(sn + (u >> 3) * 256 + (u & 7) * 8);
      }
    }
    // compute from private buf[p&1]; local px = lanelo + kx (+ nt*16)
    const bf16* rbuf = (p & 1) ? mysb1 : mysb0;
#pragma unroll
    for (int kx = 0; kx < 3; ++kx) {
      int lpx0 = lanelo + kx;
#pragma unroll
      for (int kci = 0; kci < 2; ++kci) {
        bf16x8 bv[2];
#pragma unroll
        for (int nt = 0; nt < 2; ++nt)
          bv[nt] = *(const bf16x8*)(rbuf + (lpx0 + nt * 16) * LPX + quad * 8 + kci * 32);
        __builtin_amdgcn_s_setprio(1);
#pragma unroll
        for (int mt = 0; mt < 4; ++mt)
#pragma unroll
          for (int nt = 0; nt < 2; ++nt)
            acc[mt][nt] = __builtin_amdgcn_mfma_f32_16x16x32_bf16(areg[kx][kci][mt], bv[nt], acc[mt][nt], 0, 0, 0);
        __builtin_amdgcn_s_setprio(0);
      }
    }
  }

  // epilogue: bias + BN + ReLU -> out[b][oc][y][px]
#pragma unroll
  for (int mt = 0; mt < 4; ++mt) {
#pragma unroll
    for (int nt = 0; nt < 2; ++nt) {
      int px = wq * 32 + nt * 16 + lanelo;
#pragma unroll
      for (int r = 0; r < 4; ++r) {
        int oc = mt * 16 + quad * 4 + r;
        float inv = gamma[oc] * rsqrtf(var[oc] + 1e-5f);
        float v = (acc[mt][nt][r] + cb[oc]) * inv + beta[oc] - mean[oc] * inv;
        out[((size_t)(b * 64 + oc)) * HW + y * 128 + px] = fmaxf(v, 0.0f);
      }
    }
  }
}

extern "C" void kernel_launch(void* const* d_in, const int* in_sizes, int n_in,
                              void* d_out, int out_size, void* d_ws, size_t ws_size,
                              hipStream_t stream) {
  const float* x     = (const float*)d_in[0];
  const float* kern  = (const float*)d_in[1];
  const float* mw    = (const float*)d_in[2];
  const float* mb    = (const float*)d_in[3];
  const float* w2    = (const float*)d_in[4];
  const float* cb    = (const float*)d_in[5];
  const float* gamma = (const float*)d_in[6];
  const float* beta  = (const float*)d_in[7];
  const float* mean  = (const float*)d_in[8];
  const float* var   = (const float*)d_in[9];

  float* out   = (float*)d_out;
  float* masks = out + OUT_ELEMS;

  char* ws = (char*)d_ws;
  bf16* xm_p   = (bf16*)(ws);              // 30,971,904 B
  bf16* cat_p  = (bf16*)(ws + 30971904);   // 34,611,200 B (ends 65,583,104)
  bf16* kern_t = (bf16*)(ws + 65583104);   // 884,736 B
  bf16* w2_t   = (bf16*)(ws + 66467840);   // 294,912 B -> total 66,762,752 B
  // mask partials alias CAT_P region now (xmt writes xm_p while reading part;
  // part is dead before k_branch's halo-prelude + stores touch cat_p)
  float* part  = (float*)(ws + 30971904);  // 6,291,456 B < cat_p size

  k_mask1<<<dim3(128, 4, 8), 128, 0, stream>>>(x, mw, part);
  k_xmt<<<dim3(142, 3, 4), 256, 0, stream>>>(x, part, mb, masks, xm_p, kern, w2, kern_t, w2_t);
  k_branch<<<2048, 256, 0, stream>>>(xm_p, kern_t, cat_p);
  k_final<<<512, 256, 0, stream>>>(cat_p, w2_t, cb, gamma, beta, mean, var, out);
}